// Round 6
// baseline (494.148 us; speedup 1.0000x reference)
//
#include <hip/hip_runtime.h>
#include <math.h>

#define TT 2048
#define HH 1024
#define NE 40
#define ER 32
#define II 512
#define TOPK 4
#define RSCALE 2.5f
#define MAXW 64    // max m-tiles of 256: 8192/256 + 32

typedef __bf16 bf16x8 __attribute__((ext_vector_type(8)));
typedef float f32x4 __attribute__((ext_vector_type(4)));

// ---------------- K1: fused router: logits(fp32) + softmax + top4 ----------
// fp32 logits REQUIRED (bf16 error ~2.6e-3 flips top-4 selection).
__global__ __launch_bounds__(256) void k_router(const float* __restrict__ hidden,
                                                const float* __restrict__ rw,
                                                const float* __restrict__ bias,
                                                float* __restrict__ out,
                                                int* __restrict__ tok4_id,
                                                float* __restrict__ tok4_w,
                                                __bf16* __restrict__ hid_bf) {
  int lane = threadIdx.x & 63;
  int t = blockIdx.x * 4 + (threadIdx.x >> 6);
  const float* hrow = hidden + (size_t)t * HH;
  float4 hv[4];
  #pragma unroll
  for (int c = 0; c < 4; c++) hv[c] = *(const float4*)(hrow + c * 256 + lane * 4);

  float mylg = -INFINITY;
  for (int e = 0; e < NE; e++) {
    const float* wrow = rw + (size_t)e * HH;
    float p = 0.f;
    #pragma unroll
    for (int c = 0; c < 4; c++) {
      float4 w4 = *(const float4*)(wrow + c * 256 + lane * 4);
      p += hv[c].x * w4.x + hv[c].y * w4.y + hv[c].z * w4.z + hv[c].w * w4.w;
    }
    #pragma unroll
    for (int off = 32; off; off >>= 1) p += __shfl_xor(p, off);
    if (lane == e) mylg = p;
  }
  float m = mylg;
  #pragma unroll
  for (int off = 32; off; off >>= 1) m = fmaxf(m, __shfl_xor(m, off));
  float p = (lane < NE) ? expf(mylg - m) : 0.f;
  float s = p;
  #pragma unroll
  for (int off = 32; off; off >>= 1) s += __shfl_xor(s, off);
  float score = p / s;
  float v = (lane < NE) ? score + bias[lane] : -INFINITY;
  int ids[TOPK]; float wv[TOPK];
  #pragma unroll
  for (int k = 0; k < TOPK; k++) {
    float mv = v;
    int mi = (lane < NE) ? lane : 63;
    #pragma unroll
    for (int off = 32; off; off >>= 1) {      // argmax, tie -> lower idx
      float ov = __shfl_xor(mv, off);
      int oi = __shfl_xor(mi, off);
      if (ov > mv || (ov == mv && oi < mi)) { mv = ov; mi = oi; }
    }
    ids[k] = mi;
    wv[k] = RSCALE * __shfl(score, mi);       // weight from UNBIASED score
    if (lane == mi) v = -INFINITY;
  }
  float zt = 0.f;
  #pragma unroll
  for (int k = 0; k < TOPK; k++) if (ids[k] >= ER) zt += wv[k];
  if (lane == 0) {
    #pragma unroll
    for (int k = 0; k < TOPK; k++) {
      tok4_id[t * TOPK + k] = ids[k];
      tok4_w[t * TOPK + k] = wv[k];
    }
  }
  #pragma unroll
  for (int c = 0; c < 4; c++) {
    int j = c * 256 + lane * 4;
    float4 h4 = hv[c];
    *(float4*)(out + (size_t)t * HH + j) =
        make_float4(h4.x * zt, h4.y * zt, h4.z * zt, h4.w * zt);
    union { __bf16 h[4]; uint2 u; } pk;
    pk.h[0] = (__bf16)h4.x; pk.h[1] = (__bf16)h4.y;
    pk.h[2] = (__bf16)h4.z; pk.h[3] = (__bf16)h4.w;
    *(uint2*)(hid_bf + (size_t)t * HH + j) = pk.u;
  }
}

// ---------------- K2: single-block count + scan + scatter (LDS counters) ---
__global__ __launch_bounds__(256) void k_scanscatter(const int* __restrict__ tok4_id,
                                                     const float* __restrict__ tok4_w,
                                                     int* __restrict__ cnt,
                                                     int* __restrict__ offs,
                                                     int* __restrict__ wl_e,
                                                     int* __restrict__ wl_m0,
                                                     int* __restrict__ nwork,
                                                     int* __restrict__ pair_tok,
                                                     float* __restrict__ pair_w) {
  __shared__ int scnt[32];
  __shared__ int scur[32];
  int tid = threadIdx.x;
  if (tid < 32) scnt[tid] = 0;
  __syncthreads();
  int ids[32]; float wv[32];
  #pragma unroll
  for (int i = 0; i < 32; i++) {
    int idx = i * 256 + tid;
    ids[i] = tok4_id[idx];
    wv[i] = tok4_w[idx];
    if (ids[i] < ER) atomicAdd(&scnt[ids[i]], 1);
  }
  __syncthreads();
  if (tid < 64) {
    int lane = tid;
    int c = (lane < ER) ? scnt[lane] : 0;
    int ts = (c + 255) >> 8;
    int ps = c, pt = ts;
    #pragma unroll
    for (int off = 1; off < 32; off <<= 1) {
      int v1 = __shfl_up(ps, off);
      int v2 = __shfl_up(pt, off);
      if (lane >= off) { ps += v1; pt += v2; }
    }
    if (lane < ER) {
      int o = ps - c;
      offs[lane] = o; cnt[lane] = c; scur[lane] = o;
      int tb = pt - ts;
      for (int i = 0; i < ts; i++) { wl_e[tb + i] = lane; wl_m0[tb + i] = i * 256; }
    }
    if (lane == 31) *nwork = pt;
  }
  __syncthreads();
  #pragma unroll
  for (int i = 0; i < 32; i++) {
    if (ids[i] < ER) {
      int pos = atomicAdd(&scur[ids[i]], 1);
      pair_tok[pos] = (i * 256 + tid) >> 2;
      pair_w[pos] = wv[i];
    }
  }
}

// ---------------- K3: h = silu(X@Wg^T)*(X@Wu^T), M=256, reg-prefetch -------
// grid: MAXW x 16 (32 gate + 32 up cols). Pipeline: ds_write(iter k) ->
// barrier -> FIRE global loads for k+1 -> MFMA(k) -> barrier. Loads are in
// flight through the whole compute phase (Little's law fix for the 1 TB/s
// latency-bound regime measured in R5).
__global__ __launch_bounds__(256) void k_w13(const __bf16* __restrict__ hid_bf,
                                             const float* __restrict__ w13,
                                             const int* __restrict__ cnt,
                                             const int* __restrict__ offs,
                                             const int* __restrict__ pair_tok,
                                             const int* __restrict__ wl_e,
                                             const int* __restrict__ wl_m0,
                                             const int* __restrict__ nwork,
                                             __bf16* __restrict__ h_buf) {
  int bx = blockIdx.x;
  if (bx >= *nwork) return;
  int e = wl_e[bx], m0w = wl_m0[bx];
  int M = cnt[e] - m0w; if (M > 256) M = 256;
  int base = offs[e] + m0w;
  int n0 = blockIdx.y * 32;

  __shared__ __bf16 As[256][72];   // pairs x k
  __shared__ __bf16 Bs[64][72];    // [0:32)=gate rows, [32:64)=up rows

  int tid = threadIdx.x;
  int lane = tid & 63, w = tid >> 6;
  int quad = lane >> 4, rr = lane & 15;

  const float* wg_base = w13 + (size_t)e * (2 * II) * HH + (size_t)n0 * HH;
  const float* wu_base = w13 + (size_t)e * (2 * II) * HH + (size_t)(II + n0) * HH;

  // fixed per-thread staging coordinates
  int arow = tid >> 3, acol = (tid & 7) * 8;       // A rows arow+32p, 16B col
  int brow = tid >> 4, bcol = (tid & 15) * 4;      // B rows brow+16p
  const __bf16* aptr[8];
  #pragma unroll
  for (int p = 0; p < 8; p++) {
    int r = p * 32 + arow;
    int tok = pair_tok[base + ((r < M) ? r : 0)];
    aptr[p] = hid_bf + (size_t)tok * HH + acol;
  }
  const float* bptr[4];
  #pragma unroll
  for (int p = 0; p < 4; p++) {
    int r = p * 16 + brow;
    bptr[p] = ((r < 32) ? (wg_base + (size_t)r * HH)
                        : (wu_base + (size_t)(r - 32) * HH)) + bcol;
  }

  uint4 pa[8]; float4 pb[4];
  #pragma unroll
  for (int p = 0; p < 8; p++) pa[p] = *(const uint4*)(aptr[p]);
  #pragma unroll
  for (int p = 0; p < 4; p++) pb[p] = *(const float4*)(bptr[p]);

  f32x4 accg[4][2] = {};
  f32x4 accu[4][2] = {};

  for (int k0 = 0; k0 < HH; k0 += 64) {
    #pragma unroll
    for (int p = 0; p < 8; p++) *(uint4*)&As[p * 32 + arow][acol] = pa[p];
    #pragma unroll
    for (int p = 0; p < 4; p++) {
      union { __bf16 h[4]; uint2 u; } pk;
      pk.h[0] = (__bf16)pb[p].x; pk.h[1] = (__bf16)pb[p].y;
      pk.h[2] = (__bf16)pb[p].z; pk.h[3] = (__bf16)pb[p].w;
      *(uint2*)&Bs[p * 16 + brow][bcol] = pk.u;
    }
    __syncthreads();
    if (k0 + 64 < HH) {                        // fire next tile's loads NOW
      #pragma unroll
      for (int p = 0; p < 8; p++) pa[p] = *(const uint4*)(aptr[p] + k0 + 64);
      #pragma unroll
      for (int p = 0; p < 4; p++) pb[p] = *(const float4*)(bptr[p] + k0 + 64);
    }
    #pragma unroll
    for (int ks = 0; ks < 2; ks++) {
      int kb = ks * 32 + quad * 8;
      bf16x8 a[4], bg[2], bu[2];
      #pragma unroll
      for (int i = 0; i < 4; i++) a[i] = *(const bf16x8*)&As[w * 64 + i * 16 + rr][kb];
      #pragma unroll
      for (int j = 0; j < 2; j++) {
        bg[j] = *(const bf16x8*)&Bs[j * 16 + rr][kb];
        bu[j] = *(const bf16x8*)&Bs[32 + j * 16 + rr][kb];
      }
      #pragma unroll
      for (int i = 0; i < 4; i++)
        #pragma unroll
        for (int j = 0; j < 2; j++) {
          accg[i][j] = __builtin_amdgcn_mfma_f32_16x16x32_bf16(a[i], bg[j], accg[i][j], 0, 0, 0);
          accu[i][j] = __builtin_amdgcn_mfma_f32_16x16x32_bf16(a[i], bu[j], accu[i][j], 0, 0, 0);
        }
    }
    if (k0 + 64 < HH) __syncthreads();
  }
  #pragma unroll
  for (int i = 0; i < 4; i++)
    #pragma unroll
    for (int j = 0; j < 2; j++)
      #pragma unroll
      for (int l = 0; l < 4; l++) {
        int m = w * 64 + i * 16 + quad * 4 + l;
        if (m < M) {
          float g = accg[i][j][l], u = accu[i][j][l];
          float hv = g / (1.f + expf(-g)) * u;
          h_buf[(size_t)(base + m) * II + n0 + j * 16 + rr] = (__bf16)hv;
        }
      }
}

// ---------------- K4: out[t] += w_p * (h @ w2[e]^T), M=256, reg-prefetch ---
__global__ __launch_bounds__(256) void k_w2(const __bf16* __restrict__ h_buf,
                                            const float* __restrict__ w2,
                                            const int* __restrict__ cnt,
                                            const int* __restrict__ offs,
                                            const int* __restrict__ pair_tok,
                                            const float* __restrict__ pair_w,
                                            const int* __restrict__ wl_e,
                                            const int* __restrict__ wl_m0,
                                            const int* __restrict__ nwork,
                                            float* __restrict__ out) {
  int bx = blockIdx.x;
  if (bx >= *nwork) return;
  int e = wl_e[bx], m0w = wl_m0[bx];
  int M = cnt[e] - m0w; if (M > 256) M = 256;
  int base = offs[e] + m0w;
  int h0 = blockIdx.y * 64;

  __shared__ __bf16 As[256][72];
  __shared__ __bf16 Bs[64][72];
  __shared__ int tl[256];
  __shared__ float wl[256];

  int tid = threadIdx.x;
  int lane = tid & 63, w = tid >> 6;
  int quad = lane >> 4, rr = lane & 15;

  {
    int ok = tid < M;
    tl[tid] = ok ? pair_tok[base + tid] : 0;
    wl[tid] = ok ? pair_w[base + tid] : 0.f;
  }
  const __bf16* h_base = h_buf + (size_t)base * II;
  const float* w_base = w2 + (size_t)e * HH * II + (size_t)h0 * II;

  int arow = tid >> 3, acol = (tid & 7) * 8;
  int brow = tid >> 4, bcol = (tid & 15) * 4;
  const __bf16* aptr = h_base + (size_t)arow * II + acol;   // + p*32*II + k0
  const float* bptr = w_base + (size_t)brow * II + bcol;    // + p*16*II + k0

  uint4 pa[8]; float4 pb[4];
  #pragma unroll
  for (int p = 0; p < 8; p++) pa[p] = *(const uint4*)(aptr + (size_t)p * 32 * II);
  #pragma unroll
  for (int p = 0; p < 4; p++) pb[p] = *(const float4*)(bptr + (size_t)p * 16 * II);

  f32x4 acc[4][4] = {};
  __syncthreads();

  for (int k0 = 0; k0 < II; k0 += 64) {
    #pragma unroll
    for (int p = 0; p < 8; p++) *(uint4*)&As[p * 32 + arow][acol] = pa[p];
    #pragma unroll
    for (int p = 0; p < 4; p++) {
      union { __bf16 h[4]; uint2 u; } pk;
      pk.h[0] = (__bf16)pb[p].x; pk.h[1] = (__bf16)pb[p].y;
      pk.h[2] = (__bf16)pb[p].z; pk.h[3] = (__bf16)pb[p].w;
      *(uint2*)&Bs[p * 16 + brow][bcol] = pk.u;
    }
    __syncthreads();
    if (k0 + 64 < II) {
      #pragma unroll
      for (int p = 0; p < 8; p++) pa[p] = *(const uint4*)(aptr + (size_t)p * 32 * II + k0 + 64);
      #pragma unroll
      for (int p = 0; p < 4; p++) pb[p] = *(const float4*)(bptr + (size_t)p * 16 * II + k0 + 64);
    }
    #pragma unroll
    for (int ks = 0; ks < 2; ks++) {
      int kb = ks * 32 + quad * 8;
      bf16x8 a[4], b[4];
      #pragma unroll
      for (int i = 0; i < 4; i++) a[i] = *(const bf16x8*)&As[w * 64 + i * 16 + rr][kb];
      #pragma unroll
      for (int j = 0; j < 4; j++) b[j] = *(const bf16x8*)&Bs[j * 16 + rr][kb];
      #pragma unroll
      for (int i = 0; i < 4; i++)
        #pragma unroll
        for (int j = 0; j < 4; j++)
          acc[i][j] = __builtin_amdgcn_mfma_f32_16x16x32_bf16(a[i], b[j], acc[i][j], 0, 0, 0);
    }
    if (k0 + 64 < II) __syncthreads();
  }
  #pragma unroll
  for (int i = 0; i < 4; i++)
    #pragma unroll
    for (int l = 0; l < 4; l++) {
      int m = w * 64 + i * 16 + quad * 4 + l;
      if (m < M) {
        int t = tl[m];
        float wp = wl[m];
        #pragma unroll
        for (int j = 0; j < 4; j++)
          atomicAdd(&out[(size_t)t * HH + h0 + j * 16 + rr], acc[i][j][l] * wp);
      }
    }
}

extern "C" void kernel_launch(void* const* d_in, const int* in_sizes, int n_in,
                              void* d_out, int out_size, void* d_ws, size_t ws_size,
                              hipStream_t stream) {
  const float* hidden = (const float*)d_in[0];
  const float* rw     = (const float*)d_in[1];
  const float* bias   = (const float*)d_in[2];
  const float* w13    = (const float*)d_in[3];
  const float* w2     = (const float*)d_in[4];
  float* out = (float*)d_out;

  int* ws_i = (int*)d_ws;
  int* tok4_id = ws_i;                                    // TT*4
  float* tok4_w = (float*)(tok4_id + TT * TOPK);          // TT*4
  int* pair_tok = (int*)(tok4_w + TT * TOPK);             // TT*4
  float* pair_w = (float*)(pair_tok + TT * TOPK);         // TT*4
  int* cnt = (int*)(pair_w + TT * TOPK);                  // 32
  int* offs = cnt + 32;                                   // 32
  int* wl_e = offs + 32;                                  // 64
  int* wl_m0 = wl_e + 64;                                 // 64
  int* nwork = wl_m0 + 64;                                // + pad to 16B align
  __bf16* hid_bf = (__bf16*)(nwork + 64);                 // TT*HH
  __bf16* h_buf = hid_bf + (size_t)TT * HH;               // (TT*4+256)*II

  k_router<<<dim3(TT / 4), dim3(256), 0, stream>>>(hidden, rw, bias, out,
                                                   tok4_id, tok4_w, hid_bf);
  k_scanscatter<<<dim3(1), dim3(256), 0, stream>>>(tok4_id, tok4_w, cnt, offs,
                                                   wl_e, wl_m0, nwork, pair_tok, pair_w);
  k_w13<<<dim3(MAXW, 16), dim3(256), 0, stream>>>(hid_bf, w13, cnt, offs, pair_tok,
                                                  wl_e, wl_m0, nwork, h_buf);
  k_w2<<<dim3(MAXW, 16), dim3(256), 0, stream>>>(h_buf, w2, cnt, offs, pair_tok, pair_w,
                                                 wl_e, wl_m0, nwork, out);
}